// Round 1
// baseline (929.360 us; speedup 1.0000x reference)
//
#include <hip/hip_runtime.h>
#include <math.h>

#define B_    16
#define T1_   64
#define T2_   64
#define D_    1024
#define PROJ_ 512
#define M_    (B_ * T1_ * T2_)   // 65536 rows
#define KC    32                 // K chunk
#define MT    32                 // rows per block

// ---------------------------------------------------------------------------
// Kernel A: scores[m] = sum_n v[n] * tanh( sum_k x[m,k] * W[k,n] )
// Block: 256 threads = 8 row-groups (rg) x 32 n-groups (ng).
// Each thread: 4 rows (rg*4+i) x 16 n's (ng*4 + j*128 + c), 64 fp32 accums.
// LDS: xs[KC][MT] (transposed x chunk, broadcast reads) + ws[KC*512] (W chunk).
// ---------------------------------------------------------------------------
__global__ __launch_bounds__(256) void scores_kernel(
    const float* __restrict__ x, const float* __restrict__ W,
    const float* __restrict__ v, float* __restrict__ scores) {
  __shared__ __align__(16) float xs[KC][MT];
  __shared__ __align__(16) float ws[KC * PROJ_];

  const int tid = threadIdx.x;
  const int m0  = blockIdx.x * MT;
  const int ng  = tid & 31;   // 0..31
  const int rg  = tid >> 5;   // 0..7

  float acc[4][16];
#pragma unroll
  for (int i = 0; i < 4; ++i)
#pragma unroll
    for (int j = 0; j < 16; ++j) acc[i][j] = 0.0f;

  // staging index for xs: thread loads 4 consecutive k's of one row
  const int rload = tid >> 3;        // 0..31
  const int kload = (tid & 7) * 4;   // 0,4,...,28

  for (int k0 = 0; k0 < D_; k0 += KC) {
    __syncthreads();  // protect LDS from previous iteration's readers
    // ---- stage x chunk (coalesced: 8 threads cover 128B of one row) ----
    float4 xv4 = *(const float4*)(x + (size_t)(m0 + rload) * D_ + k0 + kload);
    xs[kload + 0][rload] = xv4.x;
    xs[kload + 1][rload] = xv4.y;
    xs[kload + 2][rload] = xv4.z;
    xs[kload + 3][rload] = xv4.w;
    // ---- stage W chunk (contiguous KC*512 floats, float4 copy) ----
    {
      const float4* wsrc = (const float4*)(W + (size_t)k0 * PROJ_);
      float4* wdst = (float4*)ws;
#pragma unroll
      for (int i = 0; i < 16; ++i) wdst[tid + 256 * i] = wsrc[tid + 256 * i];
    }
    __syncthreads();
    // ---- compute ----
#pragma unroll 4
    for (int k = 0; k < KC; ++k) {
      const float4 xv = *(const float4*)&xs[k][rg * 4];   // 4 rows (broadcast)
      const float* wrow = ws + k * PROJ_;
      float4 wv[4];
#pragma unroll
      for (int j = 0; j < 4; ++j)
        wv[j] = *(const float4*)(wrow + ng * 4 + j * 128); // lane-contiguous, conflict-free
#pragma unroll
      for (int j = 0; j < 4; ++j) {
        acc[0][4 * j + 0] += xv.x * wv[j].x;
        acc[0][4 * j + 1] += xv.x * wv[j].y;
        acc[0][4 * j + 2] += xv.x * wv[j].z;
        acc[0][4 * j + 3] += xv.x * wv[j].w;
        acc[1][4 * j + 0] += xv.y * wv[j].x;
        acc[1][4 * j + 1] += xv.y * wv[j].y;
        acc[1][4 * j + 2] += xv.y * wv[j].z;
        acc[1][4 * j + 3] += xv.y * wv[j].w;
        acc[2][4 * j + 0] += xv.z * wv[j].x;
        acc[2][4 * j + 1] += xv.z * wv[j].y;
        acc[2][4 * j + 2] += xv.z * wv[j].z;
        acc[2][4 * j + 3] += xv.z * wv[j].w;
        acc[3][4 * j + 0] += xv.w * wv[j].x;
        acc[3][4 * j + 1] += xv.w * wv[j].y;
        acc[3][4 * j + 2] += xv.w * wv[j].z;
        acc[3][4 * j + 3] += xv.w * wv[j].w;
      }
    }
  }

  // ---- epilogue: tanh, dot with v, reduce across the 32 n-groups ----
  float partial[4] = {0.f, 0.f, 0.f, 0.f};
#pragma unroll
  for (int j = 0; j < 4; ++j)
#pragma unroll
    for (int c = 0; c < 4; ++c) {
      const float vv = v[ng * 4 + j * 128 + c];
#pragma unroll
      for (int i = 0; i < 4; ++i)
        partial[i] += tanhf(acc[i][4 * j + c]) * vv;
    }
#pragma unroll
  for (int i = 0; i < 4; ++i) {
    float p = partial[i];
#pragma unroll
    for (int mask = 1; mask < 32; mask <<= 1)
      p += __shfl_xor(p, mask, 64);   // masks <32 stay within each 32-lane half
    if (ng == 0) scores[m0 + rg * 4 + i] = p;
  }
}

// ---------------------------------------------------------------------------
// Kernel B: softmax over s (64 wide) + weighted sum of x -> out[b,t1,:]
// One block per (b,t1). First wave does the softmax; all 256 threads then
// accumulate 4 d-values each over the 64 s rows (float4 coalesced).
// ---------------------------------------------------------------------------
__global__ __launch_bounds__(256) void out_kernel(
    const float* __restrict__ x, const float* __restrict__ scores,
    float* __restrict__ out) {
  const int bt  = blockIdx.x;   // b*T1 + t1
  const int tid = threadIdx.x;
  __shared__ float wsm[T2_];

  if (tid < 64) {
    const float s = scores[bt * T2_ + tid];
    float m = s;
#pragma unroll
    for (int mask = 1; mask < 64; mask <<= 1)
      m = fmaxf(m, __shfl_xor(m, mask, 64));
    const float e = expf(s - m);
    float sum = e;
#pragma unroll
    for (int mask = 1; mask < 64; mask <<= 1)
      sum += __shfl_xor(sum, mask, 64);
    wsm[tid] = e / sum;
  }
  __syncthreads();

  const float* xp = x + (size_t)bt * (T2_ * D_) + tid * 4;
  float4 acc = {0.f, 0.f, 0.f, 0.f};
#pragma unroll 4
  for (int s = 0; s < T2_; ++s) {
    const float w = wsm[s];
    const float4 xv = *(const float4*)(xp + (size_t)s * D_);
    acc.x += w * xv.x;
    acc.y += w * xv.y;
    acc.z += w * xv.z;
    acc.w += w * xv.w;
  }
  *(float4*)(out + (size_t)bt * D_ + tid * 4) = acc;
}

extern "C" void kernel_launch(void* const* d_in, const int* in_sizes, int n_in,
                              void* d_out, int out_size, void* d_ws, size_t ws_size,
                              hipStream_t stream) {
  const float* x = (const float*)d_in[0];   // (16,64,64,1024) fp32
  const float* W = (const float*)d_in[1];   // (1024,512) fp32
  const float* v = (const float*)d_in[2];   // (512,) fp32
  float* out    = (float*)d_out;            // (16,64,1024) fp32
  float* scores = (float*)d_ws;             // 65536 fp32 = 256 KB scratch

  scores_kernel<<<M_ / MT, 256, 0, stream>>>(x, W, v, scores);
  out_kernel<<<B_ * T1_, 256, 0, stream>>>(x, scores, out);
}

// Round 2
// 160.864 us; speedup vs baseline: 5.7773x; 5.7773x over previous
//
#include <hip/hip_runtime.h>
#include <hip/hip_bf16.h>
#include <math.h>

#define B_    16
#define T1_   64
#define T2_   64
#define D_    1024
#define PROJ_ 512

#define BM    128          // rows per block (= 2 softmax groups of 64)
#define BK    32           // K step (= one MFMA K)
#define NT    (D_ / BK)    // 32 K-steps
#define LDP   40           // padded LDS row length (elements): 80B stride, 16B-aligned, ~2-way banks

typedef __attribute__((ext_vector_type(8))) short bf16x8;
typedef __attribute__((ext_vector_type(4))) float f32x4;

__device__ __forceinline__ unsigned short f2bf(float f) {
  __hip_bfloat16 h = __float2bfloat16(f);
  return *reinterpret_cast<unsigned short*>(&h);
}

// ---------------------------------------------------------------------------
// Kernel 0: Wt[n][k] = bf16(W[k][n])   (512 x 1024 bf16 = 1 MB in d_ws)
// ---------------------------------------------------------------------------
__global__ __launch_bounds__(256) void transpose_convert(
    const float* __restrict__ W, unsigned short* __restrict__ Wt) {
  __shared__ float tile[32][33];
  const int kt = blockIdx.x * 32;          // k tile base (0..1023)
  const int nt = blockIdx.y * 32;          // n tile base (0..511)
  const int tx = threadIdx.x & 31;
  const int ty = threadIdx.x >> 5;         // 0..7
#pragma unroll
  for (int i = 0; i < 32; i += 8)
    tile[ty + i][tx] = W[(size_t)(kt + ty + i) * PROJ_ + nt + tx];
  __syncthreads();
#pragma unroll
  for (int i = 0; i < 32; i += 8)
    Wt[(size_t)(nt + ty + i) * D_ + kt + tx] = f2bf(tile[tx][ty + i]);
}

// ---------------------------------------------------------------------------
// Fused kernel: per block of 128 rows (2 (b,t1) groups):
//   scores = v . tanh(x @ W)  via bf16 MFMA, softmax(64), out = attn . x
// 512 threads = 8 waves (2m x 4n), wave tile 64x128, acc[4][8] f32x4.
// Double-buffered LDS, reg-staged (fp32->bf16 conversion for A).
// ---------------------------------------------------------------------------
__global__ __launch_bounds__(512, 2) void fused_kernel(
    const float* __restrict__ x, const unsigned short* __restrict__ wt,
    const float* __restrict__ v, float* __restrict__ out) {
  __shared__ unsigned short As[2][BM][LDP];     // 2 x 10 KB
  __shared__ unsigned short Bs[2][PROJ_][LDP];  // 2 x 40 KB
  __shared__ float sp[BM][4];
  __shared__ float attn[BM];

  const int tid  = threadIdx.x;
  const int lane = tid & 63;
  const int wid  = tid >> 6;       // 0..7
  const int wm   = wid >> 2;       // 0..1
  const int wn   = wid & 3;        // 0..3
  const int llo  = lane & 15;
  const int lhi  = lane >> 4;      // 0..3
  const int m0   = blockIdx.x * BM;

  f32x4 acc[4][8];
#pragma unroll
  for (int mf = 0; mf < 4; ++mf)
#pragma unroll
    for (int nf = 0; nf < 8; ++nf)
      acc[mf][nf] = (f32x4){0.f, 0.f, 0.f, 0.f};

  // staging indices
  const int arow = tid >> 3;        // 0..63 (row, and row+64)
  const int akk  = (tid & 7) * 4;   // k offset within step (float4)
  const int bn   = tid >> 2;        // 0..127 (n, +128,+256,+384)
  const int bkk  = (tid & 3) * 8;   // k offset within step (8 bf16)

  const float*          xa_base = x + (size_t)(m0 + arow) * D_ + akk;
  const float*          xb_base = x + (size_t)(m0 + 64 + arow) * D_ + akk;

  float4 ra0, ra1;
  uint4  rb[4];

  // prologue: stage step 0 into regs, write buf 0
  ra0 = *(const float4*)(xa_base);
  ra1 = *(const float4*)(xb_base);
#pragma unroll
  for (int c = 0; c < 4; ++c)
    rb[c] = *(const uint4*)(wt + (size_t)(bn + 128 * c) * D_ + bkk);
  {
    ushort4 ua = {f2bf(ra0.x), f2bf(ra0.y), f2bf(ra0.z), f2bf(ra0.w)};
    ushort4 ub = {f2bf(ra1.x), f2bf(ra1.y), f2bf(ra1.z), f2bf(ra1.w)};
    *(ushort4*)&As[0][arow][akk]      = ua;
    *(ushort4*)&As[0][64 + arow][akk] = ub;
#pragma unroll
    for (int c = 0; c < 4; ++c)
      *(uint4*)&Bs[0][bn + 128 * c][bkk] = rb[c];
  }
  __syncthreads();

  for (int t = 0; t < NT; ++t) {
    const int cur = t & 1;
    // issue next-step global loads early (latency hides under MFMA)
    if (t + 1 < NT) {
      const int k1 = (t + 1) * BK;
      ra0 = *(const float4*)(xa_base + k1);
      ra1 = *(const float4*)(xb_base + k1);
#pragma unroll
      for (int c = 0; c < 4; ++c)
        rb[c] = *(const uint4*)(wt + (size_t)(bn + 128 * c) * D_ + k1 + bkk);
    }

    // compute current step from LDS
    bf16x8 af[4];
#pragma unroll
    for (int mf = 0; mf < 4; ++mf)
      af[mf] = *(const bf16x8*)&As[cur][wm * 64 + mf * 16 + llo][lhi * 8];
#pragma unroll
    for (int nf = 0; nf < 8; ++nf) {
      bf16x8 bfr = *(const bf16x8*)&Bs[cur][wn * 128 + nf * 16 + llo][lhi * 8];
#pragma unroll
      for (int mf = 0; mf < 4; ++mf)
        acc[mf][nf] = __builtin_amdgcn_mfma_f32_16x16x32_bf16(
            af[mf], bfr, acc[mf][nf], 0, 0, 0);
    }

    // write next buffer, then barrier
    if (t + 1 < NT) {
      const int nxt = cur ^ 1;
      ushort4 ua = {f2bf(ra0.x), f2bf(ra0.y), f2bf(ra0.z), f2bf(ra0.w)};
      ushort4 ub = {f2bf(ra1.x), f2bf(ra1.y), f2bf(ra1.z), f2bf(ra1.w)};
      *(ushort4*)&As[nxt][arow][akk]      = ua;
      *(ushort4*)&As[nxt][64 + arow][akk] = ub;
#pragma unroll
      for (int c = 0; c < 4; ++c)
        *(uint4*)&Bs[nxt][bn + 128 * c][bkk] = rb[c];
    }
    __syncthreads();
  }

  // ---- epilogue 1: scores partials (tanh + dot v + intra-16-lane reduce) ----
#pragma unroll
  for (int mf = 0; mf < 4; ++mf) {
    float pr[4] = {0.f, 0.f, 0.f, 0.f};
#pragma unroll
    for (int nf = 0; nf < 8; ++nf) {
      const float vv = v[wn * 128 + nf * 16 + llo];   // n = col = lane&15
#pragma unroll
      for (int r = 0; r < 4; ++r)
        pr[r] += tanhf(acc[mf][nf][r]) * vv;
    }
#pragma unroll
    for (int r = 0; r < 4; ++r) {
      float p = pr[r];
      p += __shfl_xor(p, 1, 64);
      p += __shfl_xor(p, 2, 64);
      p += __shfl_xor(p, 4, 64);
      p += __shfl_xor(p, 8, 64);
      if (llo == 0) sp[wm * 64 + mf * 16 + lhi * 4 + r][wn] = p;
    }
  }
  __syncthreads();

  // ---- epilogue 2: softmax over each 64-row group (waves 0 and 1) ----
  if (tid < BM) {
    const int row = tid;
    float s = sp[row][0] + sp[row][1] + sp[row][2] + sp[row][3];
    float mx = s;
#pragma unroll
    for (int mask = 1; mask < 64; mask <<= 1)
      mx = fmaxf(mx, __shfl_xor(mx, mask, 64));
    const float e = expf(s - mx);
    float sum = e;
#pragma unroll
    for (int mask = 1; mask < 64; mask <<= 1)
      sum += __shfl_xor(sum, mask, 64);
    attn[row] = e / sum;
  }
  __syncthreads();

  // ---- epilogue 3: out[bt, :] = sum_s attn[s] * x[bt, s, :]  ----
  const int g  = tid >> 8;          // group 0/1
  const int c4 = tid & 255;         // float4 column index (256*4 = 1024)
  const float* xg = x + (size_t)(m0 + g * 64) * D_ + c4 * 4;
  float4 o = {0.f, 0.f, 0.f, 0.f};
#pragma unroll 4
  for (int s = 0; s < T2_; ++s) {
    const float w = attn[g * 64 + s];
    const float4 xv = *(const float4*)(xg + (size_t)s * D_);
    o.x += w * xv.x;
    o.y += w * xv.y;
    o.z += w * xv.z;
    o.w += w * xv.w;
  }
  *(float4*)(out + (size_t)(blockIdx.x * 2 + g) * D_ + c4 * 4) = o;
}

extern "C" void kernel_launch(void* const* d_in, const int* in_sizes, int n_in,
                              void* d_out, int out_size, void* d_ws, size_t ws_size,
                              hipStream_t stream) {
  const float* x = (const float*)d_in[0];   // (16,64,64,1024) fp32
  const float* W = (const float*)d_in[1];   // (1024,512) fp32
  const float* v = (const float*)d_in[2];   // (512,) fp32
  float* out = (float*)d_out;               // (16,64,1024) fp32
  unsigned short* Wt = (unsigned short*)d_ws;  // 512*1024 bf16 = 1 MB

  transpose_convert<<<dim3(D_ / 32, PROJ_ / 32), 256, 0, stream>>>(W, Wt);
  fused_kernel<<<(B_ * T1_ * T2_) / BM, 512, 0, stream>>>(x, Wt, v, out);
}

// Round 3
// 127.735 us; speedup vs baseline: 7.2757x; 1.2594x over previous
//
#include <hip/hip_runtime.h>
#include <hip/hip_bf16.h>
#include <math.h>

#define B_    16
#define T1_   64
#define T2_   64
#define D_    1024
#define PROJ_ 512
#define BM    64
#define BK    32
#define NT    (D_ / BK)          // 32 K-steps
#define LDP   40                 // padded A row (shorts): 80 B stride, 16B-aligned, conflict-free

typedef __attribute__((ext_vector_type(8))) short bf16x8;
typedef __attribute__((ext_vector_type(4))) float f32x4;
typedef __attribute__((ext_vector_type(4))) unsigned int u32x4;

__device__ __forceinline__ unsigned short f2bf(float f) {
  __hip_bfloat16 h = __float2bfloat16(f);
  return *reinterpret_cast<unsigned short*>(&h);
}

// ---------------------------------------------------------------------------
// Prep: Wt fragment-ordered bf16. 16B chunk index ((t*32 + n16)*64 + lane)
// holds W[k][n] with n = n16*16 + (lane&15), k = t*32 + (lane>>4)*8 + j.
// A wave's B-fragment load is then base + lane*16 -> perfectly coalesced.
// ---------------------------------------------------------------------------
__global__ __launch_bounds__(256) void make_bfrag(
    const float* __restrict__ W, unsigned short* __restrict__ wt) {
  __shared__ float tile[32][33];
  const int t  = blockIdx.x;        // k-step 0..31
  const int np = blockIdx.y;        // n-pair 0..15
  const int tx = threadIdx.x & 31;
  const int ty = threadIdx.x >> 5;  // 0..7
#pragma unroll
  for (int i = 0; i < 4; ++i)
    tile[ty + i * 8][tx] =
        W[(size_t)(t * 32 + ty + i * 8) * PROJ_ + np * 32 + tx];
  __syncthreads();
  if (threadIdx.x < 128) {
    const int sub  = threadIdx.x >> 6;   // 0..1
    const int lane = threadIdx.x & 63;
    const int llo = lane & 15, lhi = lane >> 4;
    unsigned short o[8];
#pragma unroll
    for (int j = 0; j < 8; ++j)
      o[j] = f2bf(tile[lhi * 8 + j][sub * 16 + llo]);
    const int n16 = np * 2 + sub;
    *(u32x4*)(wt + ((size_t)(t * 32 + n16) * 64 + lane) * 8) = *(const u32x4*)o;
  }
}

// ---------------------------------------------------------------------------
// Fused: per block = one (b,t1) group of 64 rows.
//   scores = v . tanh(x @ W) via bf16 MFMA -> softmax(64) -> out = attn . x
// 512 threads = 8 waves, wave-tile 64 rows x 64 cols (wid = n-slice).
// A: reg-staged fp32->bf16 into padded LDS (double-buffered).
// B: register fragments straight from L2-resident fragment-ordered Wt.
// ---------------------------------------------------------------------------
__global__ __launch_bounds__(512, 4) void fused_kernel(
    const float* __restrict__ x, const unsigned short* __restrict__ wt,
    const float* __restrict__ v, float* __restrict__ out) {
  __shared__ unsigned short As[2][BM][LDP];   // 10.2 KB
  __shared__ float sp[BM][9];                 // per-wave score partials
  __shared__ float attn[BM];
  __shared__ f32x4 xred[256];                 // epilogue s-split reduce

  const int tid  = threadIdx.x;
  const int lane = tid & 63;
  const int wid  = tid >> 6;            // 0..7 = 64-col n-slice
  const int llo  = lane & 15, lhi = lane >> 4;
  const int bt   = blockIdx.x;          // (b,t1)
  const int m0   = bt * BM;

  f32x4 acc[4][4];
#pragma unroll
  for (int mf = 0; mf < 4; ++mf)
#pragma unroll
    for (int nf = 0; nf < 4; ++nf) acc[mf][nf] = (f32x4){0.f, 0.f, 0.f, 0.f};

  // A staging map: thread -> row = tid/8, k-chunk = (tid&7)*4 (one float4)
  const int arow = tid >> 3, akc = (tid & 7) * 4;
  const float* asrc = x + (size_t)(m0 + arow) * D_ + akc;

  // B fragment base: u32x4 index = (t*32 + wid*4 + nf)*64 + lane
  const u32x4* wt4 = (const u32x4*)wt;
  const int bbase = (wid * 4) * 64 + lane;

  // prologue: stage A(0), issue B(0)
  {
    float4 ra = *(const float4*)(asrc);
    ushort4 ua = {f2bf(ra.x), f2bf(ra.y), f2bf(ra.z), f2bf(ra.w)};
    *(ushort4*)&As[0][arow][akc] = ua;
  }
  u32x4 rb[4];
#pragma unroll
  for (int nf = 0; nf < 4; ++nf) rb[nf] = wt4[bbase + nf * 64];

#pragma unroll 2
  for (int t = 0; t < NT; ++t) {
    const int cur = t & 1;
    __syncthreads();                    // As[cur] visible to all waves

    float4 ra;
    if (t + 1 < NT) ra = *(const float4*)(asrc + (t + 1) * BK);  // issue early

    bf16x8 af[4];
#pragma unroll
    for (int mf = 0; mf < 4; ++mf)
      af[mf] = *(const bf16x8*)&As[cur][mf * 16 + llo][lhi * 8];

#pragma unroll
    for (int nf = 0; nf < 4; ++nf) {
      bf16x8 bfr = *(const bf16x8*)&rb[nf];
#pragma unroll
      for (int mf = 0; mf < 4; ++mf)
        acc[mf][nf] = __builtin_amdgcn_mfma_f32_16x16x32_bf16(
            af[mf], bfr, acc[mf][nf], 0, 0, 0);
      if (t + 1 < NT)                   // refresh right after last use
        rb[nf] = wt4[bbase + (t + 1) * 2048 + nf * 64];
    }

    if (t + 1 < NT) {                   // convert + write next A buffer
      ushort4 ua = {f2bf(ra.x), f2bf(ra.y), f2bf(ra.z), f2bf(ra.w)};
      *(ushort4*)&As[cur ^ 1][arow][akc] = ua;
    }
  }

  // ---- epilogue 1: tanh + dot(v-slice) + 16-lane reduce -> sp[row][wid] ----
#pragma unroll
  for (int mf = 0; mf < 4; ++mf) {
    float pr[4] = {0.f, 0.f, 0.f, 0.f};
#pragma unroll
    for (int nf = 0; nf < 4; ++nf) {
      const float vv = v[wid * 64 + nf * 16 + llo];   // col = lane&15
#pragma unroll
      for (int r = 0; r < 4; ++r)
        pr[r] += tanhf(acc[mf][nf][r]) * vv;
    }
#pragma unroll
    for (int r = 0; r < 4; ++r) {
      float p = pr[r];
      p += __shfl_xor(p, 1, 64);
      p += __shfl_xor(p, 2, 64);
      p += __shfl_xor(p, 4, 64);
      p += __shfl_xor(p, 8, 64);
      if (llo == 0) sp[mf * 16 + lhi * 4 + r][wid] = p;  // row = (lane>>4)*4+r
    }
  }
  __syncthreads();

  // ---- epilogue 2: softmax over the 64 rows (wave 0) ----
  if (tid < BM) {
    float s = 0.f;
#pragma unroll
    for (int w = 0; w < 8; ++w) s += sp[tid][w];
    float mx = s;
#pragma unroll
    for (int mask = 1; mask < 64; mask <<= 1)
      mx = fmaxf(mx, __shfl_xor(mx, mask, 64));
    const float e = expf(s - mx);
    float sum = e;
#pragma unroll
    for (int mask = 1; mask < 64; mask <<= 1)
      sum += __shfl_xor(sum, mask, 64);
    attn[tid] = e / sum;
  }
  __syncthreads();

  // ---- epilogue 3: out = sum_s attn[s] * x[m0+s][:], s split over 2 halves ----
  const int c4 = tid & 255;             // float4 column 0..255
  const int sh = tid >> 8;              // s-half 0/1
  const float* xg = x + (size_t)m0 * D_ + c4 * 4;
  f32x4 o = {0.f, 0.f, 0.f, 0.f};
#pragma unroll 4
  for (int s = sh * 32; s < sh * 32 + 32; ++s) {
    const float w = attn[s];
    const float4 xv = *(const float4*)(xg + (size_t)s * D_);
    o[0] += w * xv.x; o[1] += w * xv.y; o[2] += w * xv.z; o[3] += w * xv.w;
  }
  if (sh == 1) xred[c4] = o;
  __syncthreads();
  if (sh == 0) {
    f32x4 o2 = xred[c4];
    float4 res = {o[0] + o2[0], o[1] + o2[1], o[2] + o2[2], o[3] + o2[3]};
    *(float4*)(out + (size_t)bt * D_ + c4 * 4) = res;
  }
}

extern "C" void kernel_launch(void* const* d_in, const int* in_sizes, int n_in,
                              void* d_out, int out_size, void* d_ws, size_t ws_size,
                              hipStream_t stream) {
  const float* x = (const float*)d_in[0];   // (16,64,64,1024) fp32
  const float* W = (const float*)d_in[1];   // (1024,512) fp32
  const float* v = (const float*)d_in[2];   // (512,) fp32
  float* out = (float*)d_out;               // (16,64,1024) fp32
  unsigned short* Wt = (unsigned short*)d_ws;  // 32*32*64*8 bf16 = 1 MB

  make_bfrag<<<dim3(NT, PROJ_ / 32), 256, 0, stream>>>(W, Wt);
  fused_kernel<<<B_ * T1_, 512, 0, stream>>>(x, Wt, v, out);
}

// Round 4
// 113.910 us; speedup vs baseline: 8.1587x; 1.1214x over previous
//
#include <hip/hip_runtime.h>
#include <hip/hip_bf16.h>
#include <math.h>

#define B_    16
#define T1_   64
#define T2_   64
#define D_    1024
#define PROJ_ 512
#define BM    64
#define BK    32
#define NT    (D_ / BK)          // 32 K-steps
#define LDP   40                 // padded A row (shorts): 80 B stride, 2-way banks = free

typedef __attribute__((ext_vector_type(8))) short bf16x8;
typedef __attribute__((ext_vector_type(4))) float f32x4;
typedef __attribute__((ext_vector_type(4))) unsigned int u32x4;

// RNE fp32->bf16, no NaN path (inputs are finite)
__device__ __forceinline__ unsigned short f2bf(float f) {
  unsigned int u = __builtin_bit_cast(unsigned int, f);
  u += 0x7FFFu + ((u >> 16) & 1u);
  return (unsigned short)(u >> 16);
}

// tanh(a) = 1 - 2/(exp(2a)+1); v_exp_f32 + v_rcp_f32, ~5 instr, |err|~1e-6
__device__ __forceinline__ float fast_tanh(float a) {
  float t = __builtin_amdgcn_exp2f(a * 2.885390081777927f);  // exp(2a)
  return 1.0f - 2.0f * __builtin_amdgcn_rcpf(t + 1.0f);
}

// ---------------------------------------------------------------------------
// Prep: Wt fragment-ordered bf16. 16B chunk index ((t*32 + n16)*64 + lane)
// holds W[k][n], n = n16*16 + (lane&15), k = t*32 + (lane>>4)*8 + j.
// ---------------------------------------------------------------------------
__global__ __launch_bounds__(256) void make_bfrag(
    const float* __restrict__ W, unsigned short* __restrict__ wt) {
  __shared__ float tile[32][33];
  const int t  = blockIdx.x;        // k-step 0..31
  const int np = blockIdx.y;        // n-pair 0..15
  const int tx = threadIdx.x & 31;
  const int ty = threadIdx.x >> 5;  // 0..7
#pragma unroll
  for (int i = 0; i < 4; ++i)
    tile[ty + i * 8][tx] =
        W[(size_t)(t * 32 + ty + i * 8) * PROJ_ + np * 32 + tx];
  __syncthreads();
  if (threadIdx.x < 128) {
    const int sub  = threadIdx.x >> 6;   // 0..1
    const int lane = threadIdx.x & 63;
    const int llo = lane & 15, lhi = lane >> 4;
    unsigned short o[8];
#pragma unroll
    for (int j = 0; j < 8; ++j)
      o[j] = f2bf(tile[lhi * 8 + j][sub * 16 + llo]);
    const int n16 = np * 2 + sub;
    *(u32x4*)(wt + ((size_t)(t * 32 + n16) * 64 + lane) * 8) = *(const u32x4*)o;
  }
}

// ---------------------------------------------------------------------------
// Fused: one (b,t1) group of 64 rows per block.
// scores = v . tanh(x @ W) via bf16 MFMA -> softmax(64) -> out = attn . x
// 512 threads = 8 waves (wid = 64-col n-slice), wave-tile 64x64, acc[4][4].
// A: depth-2 register pipeline (named slots s0/s1) -> bf16 LDS double-buffer.
// B: register fragments from L2-resident fragment-ordered Wt (depth-1).
// ---------------------------------------------------------------------------
__global__ __launch_bounds__(512, 4) void fused_kernel(
    const float* __restrict__ x, const unsigned short* __restrict__ wt,
    const float* __restrict__ v, float* __restrict__ out) {
  __shared__ unsigned short As[2][BM][LDP];   // 10.2 KB
  __shared__ float sp[BM][9];
  __shared__ float attn[BM];
  __shared__ f32x4 xred[256];

  const int tid  = threadIdx.x;
  const int lane = tid & 63;
  const int wid  = tid >> 6;            // 0..7
  const int llo  = lane & 15, lhi = lane >> 4;
  const int bt   = blockIdx.x;
  const int m0   = bt * BM;

  f32x4 acc[4][4];
#pragma unroll
  for (int mf = 0; mf < 4; ++mf)
#pragma unroll
    for (int nf = 0; nf < 4; ++nf) acc[mf][nf] = (f32x4){0.f, 0.f, 0.f, 0.f};

  const int arow = tid >> 3, akc = (tid & 7) * 4;
  const float* asrc = x + (size_t)(m0 + arow) * D_ + akc;

  const u32x4* wt4 = (const u32x4*)wt;
  const int bbase = (wid * 4) * 64 + lane;

  // prologue: depth-2 A pipeline + B(0)
  float4 s0 = *(const float4*)(asrc);
  float4 s1 = *(const float4*)(asrc + BK);
  u32x4 rb[4];
#pragma unroll
  for (int nf = 0; nf < 4; ++nf) rb[nf] = wt4[bbase + nf * 64];
  {
    ushort4 ua = {f2bf(s0.x), f2bf(s0.y), f2bf(s0.z), f2bf(s0.w)};
    *(ushort4*)&As[0][arow][akc] = ua;
  }

#define KSTEP(T, SLD, SCV, BR, BW)                                           \
  {                                                                          \
    __syncthreads();                                                         \
    bf16x8 af0 = *(const bf16x8*)&As[BR][ 0 + llo][lhi * 8];                 \
    bf16x8 af1 = *(const bf16x8*)&As[BR][16 + llo][lhi * 8];                 \
    bf16x8 af2 = *(const bf16x8*)&As[BR][32 + llo][lhi * 8];                 \
    bf16x8 af3 = *(const bf16x8*)&As[BR][48 + llo][lhi * 8];                 \
    if ((T) + 2 < NT) SLD = *(const float4*)(asrc + ((T) + 2) * BK);         \
    _Pragma("unroll")                                                        \
    for (int nf = 0; nf < 4; ++nf) {                                         \
      bf16x8 bfr = *(const bf16x8*)&rb[nf];                                  \
      acc[0][nf] = __builtin_amdgcn_mfma_f32_16x16x32_bf16(af0, bfr, acc[0][nf], 0, 0, 0); \
      acc[1][nf] = __builtin_amdgcn_mfma_f32_16x16x32_bf16(af1, bfr, acc[1][nf], 0, 0, 0); \
      acc[2][nf] = __builtin_amdgcn_mfma_f32_16x16x32_bf16(af2, bfr, acc[2][nf], 0, 0, 0); \
      acc[3][nf] = __builtin_amdgcn_mfma_f32_16x16x32_bf16(af3, bfr, acc[3][nf], 0, 0, 0); \
      if ((T) + 1 < NT) rb[nf] = wt4[bbase + ((T) + 1) * 2048 + nf * 64];    \
    }                                                                        \
    if ((T) + 1 < NT) {                                                      \
      ushort4 ua = {f2bf(SCV.x), f2bf(SCV.y), f2bf(SCV.z), f2bf(SCV.w)};     \
      *(ushort4*)&As[BW][arow][akc] = ua;                                    \
    }                                                                        \
  }

  for (int t = 0; t < NT; t += 2) {
    KSTEP(t,     s0, s1, 0, 1)
    KSTEP(t + 1, s1, s0, 1, 0)
  }
#undef KSTEP

  // ---- epilogue 1: tanh + dot(v-slice) + 16-lane reduce -> sp[row][wid] ----
  float vv0 = v[wid * 64 +  0 + llo];
  float vv1 = v[wid * 64 + 16 + llo];
  float vv2 = v[wid * 64 + 32 + llo];
  float vv3 = v[wid * 64 + 48 + llo];
#pragma unroll
  for (int mf = 0; mf < 4; ++mf) {
    float pr[4] = {0.f, 0.f, 0.f, 0.f};
#pragma unroll
    for (int r = 0; r < 4; ++r) {
      pr[r] += fast_tanh(acc[mf][0][r]) * vv0;
      pr[r] += fast_tanh(acc[mf][1][r]) * vv1;
      pr[r] += fast_tanh(acc[mf][2][r]) * vv2;
      pr[r] += fast_tanh(acc[mf][3][r]) * vv3;
    }
#pragma unroll
    for (int r = 0; r < 4; ++r) {
      float p = pr[r];
      p += __shfl_xor(p, 1, 64);
      p += __shfl_xor(p, 2, 64);
      p += __shfl_xor(p, 4, 64);
      p += __shfl_xor(p, 8, 64);
      if (llo == 0) sp[mf * 16 + lhi * 4 + r][wid] = p;
    }
  }
  __syncthreads();

  // ---- epilogue 2: softmax over the 64 rows (wave 0) ----
  if (tid < BM) {
    float s = 0.f;
#pragma unroll
    for (int w = 0; w < 8; ++w) s += sp[tid][w];
    float mx = s;
#pragma unroll
    for (int mask = 1; mask < 64; mask <<= 1)
      mx = fmaxf(mx, __shfl_xor(mx, mask, 64));
    const float e = __builtin_amdgcn_exp2f((s - mx) * 1.442695040888963f);
    float sum = e;
#pragma unroll
    for (int mask = 1; mask < 64; mask <<= 1)
      sum += __shfl_xor(sum, mask, 64);
    attn[tid] = e * __builtin_amdgcn_rcpf(sum);
  }
  __syncthreads();

  // ---- epilogue 3: out = sum_s attn[s]*x[m0+s][:], 2-way s-split, MLP=4 ----
  const int c4 = tid & 255;
  const int sh = tid >> 8;
  const float* xg = x + ((size_t)m0 + sh * 32) * D_ + c4 * 4;
  f32x4 o0 = {0.f,0.f,0.f,0.f}, o1 = o0, o2 = o0, o3 = o0;
#pragma unroll
  for (int s = 0; s < 32; s += 4) {
    const float w0 = attn[sh * 32 + s + 0];
    const float w1 = attn[sh * 32 + s + 1];
    const float w2 = attn[sh * 32 + s + 2];
    const float w3 = attn[sh * 32 + s + 3];
    const float4 a0 = *(const float4*)(xg + (size_t)(s + 0) * D_);
    const float4 a1 = *(const float4*)(xg + (size_t)(s + 1) * D_);
    const float4 a2 = *(const float4*)(xg + (size_t)(s + 2) * D_);
    const float4 a3 = *(const float4*)(xg + (size_t)(s + 3) * D_);
    o0[0] += w0 * a0.x; o0[1] += w0 * a0.y; o0[2] += w0 * a0.z; o0[3] += w0 * a0.w;
    o1[0] += w1 * a1.x; o1[1] += w1 * a1.y; o1[2] += w1 * a1.z; o1[3] += w1 * a1.w;
    o2[0] += w2 * a2.x; o2[1] += w2 * a2.y; o2[2] += w2 * a2.z; o2[3] += w2 * a2.w;
    o3[0] += w3 * a3.x; o3[1] += w3 * a3.y; o3[2] += w3 * a3.z; o3[3] += w3 * a3.w;
  }
  f32x4 o;
#pragma unroll
  for (int j = 0; j < 4; ++j) o[j] = (o0[j] + o1[j]) + (o2[j] + o3[j]);
  if (sh == 1) xred[c4] = o;
  __syncthreads();
  if (sh == 0) {
    f32x4 o2b = xred[c4];
    float4 res = {o[0] + o2b[0], o[1] + o2b[1], o[2] + o2b[2], o[3] + o2b[3]};
    *(float4*)(out + (size_t)bt * D_ + c4 * 4) = res;
  }
}

extern "C" void kernel_launch(void* const* d_in, const int* in_sizes, int n_in,
                              void* d_out, int out_size, void* d_ws, size_t ws_size,
                              hipStream_t stream) {
  const float* x = (const float*)d_in[0];   // (16,64,64,1024) fp32
  const float* W = (const float*)d_in[1];   // (1024,512) fp32
  const float* v = (const float*)d_in[2];   // (512,) fp32
  float* out = (float*)d_out;               // (16,64,1024) fp32
  unsigned short* Wt = (unsigned short*)d_ws;  // 1 MB fragment-ordered bf16

  make_bfrag<<<dim3(NT, PROJ_ / 32), 256, 0, stream>>>(W, Wt);
  fused_kernel<<<B_ * T1_, 512, 0, stream>>>(x, Wt, v, out);
}